// Round 16
// baseline (375.076 us; speedup 1.0000x reference)
//
#include <hip/hip_runtime.h>
#include <math.h>

// Problem constants
#define GG 256            // graphs
#define NN 128            // nodes per graph
#define NTOT (GG*NN)      // 32768
#define EPG 2048          // edges per graph (N*DEG)
#define EDGES (GG*EPG)    // 524288
#define HID 256
#define DH 64             // head dim (HID/4)

typedef __attribute__((ext_vector_type(8))) short short8;
typedef __attribute__((ext_vector_type(4))) float f32x4;

__device__ __forceinline__ ushort f2bf(float f){
  union { float f; unsigned u; } x; x.f = f;
  unsigned r = x.u + 0x7fffu + ((x.u >> 16) & 1u);   // RNE
  return (ushort)(r >> 16);
}
__device__ __forceinline__ float bf2f(ushort h){
  union { unsigned u; float f; } x; x.u = ((unsigned)h) << 16;
  return x.f;
}
// Node permutation within each 64-row block: plane position p holds row R(p).
__device__ __forceinline__ int permR(int p){
  return ((p>>2)&3)*16 + ((p>>4)&3)*4 + (p&3) + (p&64);
}
#define BN_INVN (1.0f/32768.0f)

// ---------------------------------------------------------------------------
// Shared inline bodies for the fat prep kernel
// ---------------------------------------------------------------------------
struct PrepW { const float* w; int K; int N; };
struct PrepArgs { PrepW e[16]; };

// fp32 W[K,N] -> bf16 Wt[N,K], one 64x64 tile (whole block participates)
__device__ __forceinline__ void prepw_body(char* smem, const float* W, int K, int N,
                                           ushort* out, int tk, int tn)
{
  ushort (*T)[72] = (ushort (*)[72])smem;
  int t = threadIdx.x;
  int kr = t>>2, n0 = (t&3)*16;
  #pragma unroll
  for (int j=0;j<4;j++){
    float4 v = *(const float4*)(W + (size_t)(tk*64+kr)*N + tn*64 + n0 + j*4);
    T[n0+j*4+0][kr] = f2bf(v.x);
    T[n0+j*4+1][kr] = f2bf(v.y);
    T[n0+j*4+2][kr] = f2bf(v.z);
    T[n0+j*4+3][kr] = f2bf(v.w);
  }
  __syncthreads();
  int nr = t>>2, k0 = (t&3)*16;
  *(short8*)(out + (size_t)(tn*64+nr)*K + tk*64 + k0)     = *(short8*)&T[nr][k0];
  *(short8*)(out + (size_t)(tn*64+nr)*K + tk*64 + k0 + 8) = *(short8*)&T[nr][k0+8];
}

// fp32 tiled matmul 64x64 tile: out[M,N] = A[M,K]@W[K,N] + bias
__device__ __forceinline__ void mmk_body(char* smem, const float* A, const float* W,
    const float* bias, float* out, int bm, int bn, int M, int K, int N)
{
  float (*As)[68] = (float (*)[68])smem;              // [16][68]
  float (*Ws)[68] = (float (*)[68])(smem + 16*68*4);  // [16][68]
  const int t  = threadIdx.x;
  const int tx = t & 15, ty = t >> 4;
  const int lrow = t >> 2;
  const int lkc  = (t & 3) * 4;
  const int wkr  = t >> 4;
  const int wnc  = (t & 15) * 4;
  float acc[4][4] = {{0.f}};
  for (int k0 = 0; k0 < K; k0 += 16) {
    float4 av = make_float4(0.f,0.f,0.f,0.f);
    if (bm + lrow < M) av = *(const float4*)(A + (size_t)(bm+lrow)*K + k0 + lkc);
    float4 wv = *(const float4*)(W + (size_t)(k0+wkr)*N + bn + wnc);
    As[lkc+0][lrow]=av.x; As[lkc+1][lrow]=av.y; As[lkc+2][lrow]=av.z; As[lkc+3][lrow]=av.w;
    *(float4*)&Ws[wkr][wnc] = wv;
    __syncthreads();
    #pragma unroll
    for (int kk=0; kk<16; kk++){
      float4 a4 = *(float4*)&As[kk][ty*4];
      float4 b4 = *(float4*)&Ws[kk][tx*4];
      acc[0][0]+=a4.x*b4.x; acc[0][1]+=a4.x*b4.y; acc[0][2]+=a4.x*b4.z; acc[0][3]+=a4.x*b4.w;
      acc[1][0]+=a4.y*b4.x; acc[1][1]+=a4.y*b4.y; acc[1][2]+=a4.y*b4.z; acc[1][3]+=a4.y*b4.w;
      acc[2][0]+=a4.z*b4.x; acc[2][1]+=a4.z*b4.y; acc[2][2]+=a4.z*b4.z; acc[2][3]+=a4.z*b4.w;
      acc[3][0]+=a4.w*b4.x; acc[3][1]+=a4.w*b4.y; acc[3][2]+=a4.w*b4.z; acc[3][3]+=a4.w*b4.w;
    }
    __syncthreads();
  }
  #pragma unroll
  for (int i=0;i<4;i++){
    int r = bm + ty*4 + i;
    if (r >= M) continue;
    #pragma unroll
    for (int j=0;j<4;j++){
      int c = bn + tx*4 + j;
      float v = acc[i][j] + (bias ? bias[c] : 0.f);
      out[(size_t)r*N + c] = v;
    }
  }
}

// ---------------------------------------------------------------------------
// FAT PREP: one dispatch for all input-only work.
// blocks [0,256)  : prep_weights (16 weights x 16 tiles)
// blocks [256,512): adj_build (256 graphs)
// blocks [512,528): tmpK = lin1_W @ p1_Wk   (4x4 tiles)
// blocks [528,544): tmpV = lin1_W @ p1_Wv
// blocks [544,546): comb_bias
// blocks [546,554): qp1 = S1@p1_Wq + bq   (75x256, 2x4 tiles)
// blocks [554,558): qp3 = S3@p3_Wq + bq   (1x256, 1x4 tiles)
// block  558      : zero the 4x512 BN atomic-sum buffers
// ---------------------------------------------------------------------------
__global__ __launch_bounds__(256) void fat_prep(
    PrepArgs pa, ushort* __restrict__ wtb,
    const int* __restrict__ src, const int* __restrict__ dst,
    ushort* __restrict__ adjg, float* __restrict__ dinv,
    const float* lin1_W, const float* p1_Wk, const float* p1_Wv,
    const float* lin1_b, float* bcomb, float* tmpK, float* tmpV,
    const float* S1, const float* p1_Wq, const float* p1_bq, float* qp1,
    const float* S3, const float* p3_Wq, const float* p3_bq, float* qp3,
    float* bnsums)
{
  __shared__ char smem[65536];
  const int b = blockIdx.x;
  const int t = threadIdx.x;

  if (b < 256){
    int wi = b>>4, tile = b&15;
    const float* W = pa.e[wi].w;
    int K = pa.e[wi].K, N = pa.e[wi].N;
    int tk_n = K>>6, tn_n = N>>6;
    if (tile >= tk_n*tn_n) return;
    prepw_body(smem, W, K, N, wtb + (size_t)wi*65536, tile % tk_n, tile / tk_n);
  } else if (b < 512){
    int g = b - 256;
    unsigned* hist = (unsigned*)smem;               // [NN*NN] 64KB
    int base = g*EPG, nb = g*NN;
    for (int i=t; i<NN*NN; i+=256) hist[i]=0u;
    __syncthreads();
    {
      int4 a = *(const int4*)(src + base + t*8);
      int4 bb = *(const int4*)(src + base + t*8 + 4);
      int4 c = *(const int4*)(dst + base + t*8);
      int4 d = *(const int4*)(dst + base + t*8 + 4);
      atomicAdd(&hist[(a.x-nb)*NN + (c.x-nb)], 1u);
      atomicAdd(&hist[(a.y-nb)*NN + (c.y-nb)], 1u);
      atomicAdd(&hist[(a.z-nb)*NN + (c.z-nb)], 1u);
      atomicAdd(&hist[(a.w-nb)*NN + (c.w-nb)], 1u);
      atomicAdd(&hist[(bb.x-nb)*NN + (d.x-nb)], 1u);
      atomicAdd(&hist[(bb.y-nb)*NN + (d.y-nb)], 1u);
      atomicAdd(&hist[(bb.z-nb)*NN + (d.z-nb)], 1u);
      atomicAdd(&hist[(bb.w-nb)*NN + (d.w-nb)], 1u);
    }
    __syncthreads();
    if (t < NN){
      unsigned dg = 0;
      for (int k=0; k<NN; k++) dg += hist[k*NN + t];
      dinv[nb + t] = rsqrtf((float)dg + 1.0f);
    }
    __syncthreads();
    ushort* out = adjg + (size_t)g*NN*NN;
    for (int idx=t; idx<NN*NN; idx+=256){
      int i = idx >> 7, kp = idx & 127;
      int j = permR(kp);
      unsigned cnt = hist[j*NN + i];
      float v = (float)cnt + ((i==j) ? 1.0f : 0.0f);
      out[idx] = f2bf(v);
    }
  } else if (b < 528){
    int idx = b - 512;
    mmk_body(smem, lin1_W, p1_Wk, nullptr, tmpK, (idx&3)*64, (idx>>2)*64, 256,256,256);
  } else if (b < 544){
    int idx = b - 528;
    mmk_body(smem, lin1_W, p1_Wv, nullptr, tmpV, (idx&3)*64, (idx>>2)*64, 256,256,256);
  } else if (b < 546){
    int sel = b - 544;
    const float* W = sel ? p1_Wv : p1_Wk;
    float s = 0.f;
    for (int k=0;k<256;k++) s += lin1_b[k]*W[k*256+t];
    bcomb[sel*256+t] = s;
  } else if (b < 554){
    int idx = b - 546;                               // (2,4): bx=idx&1, by=idx>>1
    mmk_body(smem, S1, p1_Wq, p1_bq, qp1, (idx&1)*64, (idx>>1)*64, 75,256,HID);
  } else if (b < 558){
    int idx = b - 554;                               // (1,4)
    mmk_body(smem, S3, p3_Wq, p3_bq, qp3, 0, idx*64, 1,256,HID);
  } else {
    #pragma unroll
    for (int e=0;e<8;e++) bnsums[t*8+e] = 0.f;       // 2048 floats: 4 BN buffers
  }
}

// ---------------------------------------------------------------------------
// Weight prep standalone (for the folded lin1+KV weights, after fat_prep)
// ---------------------------------------------------------------------------
__global__ __launch_bounds__(256) void prep_weights(PrepArgs pa, ushort* __restrict__ wtb)
{
  __shared__ char smem[9216];
  int wi = blockIdx.x;
  const float* W = pa.e[wi].w;
  int K = pa.e[wi].K, N = pa.e[wi].N;
  int tk_n = K>>6, tn_n = N>>6;
  int tile = blockIdx.y;
  if (tile >= tk_n*tn_n) return;
  prepw_body(smem, W, K, N, wtb + (size_t)wi*65536, tile % tk_n, tile / tk_n);
}

// ---------------------------------------------------------------------------
// LDS-free dense aggregation: out[128][256] = Adj[128x128] @ X (per graph).
// B read from permuted bf16 planes (plane[col][node], NTOT per column).
// MODE 1: GIN-1, f = relu(v*scl+shf); stats computed INLINE from atomic sums
//         (aux = {sum[256], sumsq[256]}, b0 = gamma, b1 = beta).
// MODE 2: GCN, planes hold xw*dinv_j; epilogue v = v*dinv_i + bias.
// MODE 3: GIN-0 (reassociated): plain agg + bias + BN partial atomicAdd into
//         part ({sum[256], sumsq[256]}).
// OUTBF=1: write bf16 (f2bf(v)).
// ---------------------------------------------------------------------------
template<int MODE, int OUTBF>
__global__ __launch_bounds__(256) void agg_gemm(
    const ushort* __restrict__ adjg,
    const ushort* __restrict__ P0, const ushort* __restrict__ P1,
    const float* __restrict__ aux,       // sums (MODE1) or dinv (MODE2)
    const float* __restrict__ b0, const float* __restrict__ b1,
    void* __restrict__ out0v, void* __restrict__ out1v,
    float* __restrict__ part)
{
  const int g = blockIdx.x;
  int bn, sel = 0;
  if (MODE==2){ sel = blockIdx.y >> 1; bn = (blockIdx.y & 1)*128; }
  else bn = blockIdx.y*128;
  const ushort* Ph = (MODE==2 && sel) ? P1 : P0;
  const float* bias = (MODE==2) ? (sel ? b1 : b0) : b0;
  void* outv = (MODE==2 && sel) ? out1v : out0v;
  const int t = threadIdx.x;
  const int w = t>>6, l = t&63;
  const int wr = w>>1, wc = w&1;
  const int c16 = l&15, g16 = l>>4;
  const size_t nbase = (size_t)g*NN;
  f32x4 acc[4][4];
  #pragma unroll
  for (int i=0;i<4;i++)
    #pragma unroll
    for (int j=0;j<4;j++) acc[i][j] = (f32x4){0.f,0.f,0.f,0.f};
  const ushort* ag = adjg + (size_t)g*NN*NN;

  float sclj[4], shfj[4];
  if (MODE==1){
    #pragma unroll
    for (int j=0;j<4;j++){
      int col = bn + wc*64 + j*16 + c16;
      float s = aux[col], s2v = aux[256+col];
      float mean = s*BN_INVN;
      float var  = s2v*BN_INVN - mean*mean;
      float scl  = b0[col]*rsqrtf(var + 1e-5f);
      sclj[j] = scl;
      shfj[j] = b1[col] - mean*scl;
    }
  }

  for (int kk=0; kk<128; kk+=32){
    short8 af[4];
    #pragma unroll
    for (int i=0;i<4;i++)
      af[i] = *(const short8*)(ag + (wr*64+i*16+c16)*NN + kk + g16*8);
    short8 bh[4];
    size_t off = nbase + kk + g16*8;
    #pragma unroll
    for (int j=0;j<4;j++){
      int col = bn + wc*64 + j*16 + c16;
      short8 h8 = *(const short8*)(Ph + (size_t)col*NTOT + off);
      if (MODE==1){
        #pragma unroll
        for (int e=0;e<8;e++){
          float v = bf2f((ushort)h8[e]);
          v = fmaxf(v*sclj[j] + shfj[j], 0.f);
          h8[e] = (short)f2bf(v);
        }
      }
      bh[j] = h8;
    }
    #pragma unroll
    for (int i=0;i<4;i++)
      #pragma unroll
      for (int j=0;j<4;j++)
        acc[i][j] = __builtin_amdgcn_mfma_f32_16x16x32_bf16(af[i], bh[j], acc[i][j], 0,0,0);
  }
  float sj[4]  = {0.f,0.f,0.f,0.f};
  float s2j[4] = {0.f,0.f,0.f,0.f};
  #pragma unroll
  for (int i=0;i<4;i++){
    float4 di4 = make_float4(1.f,1.f,1.f,1.f);
    if (MODE==2) di4 = *(const float4*)(aux + nbase + wr*64 + i*16 + g16*4);
    #pragma unroll
    for (int j=0;j<4;j++){
      int col = bn + wc*64 + j*16 + c16;
      #pragma unroll
      for (int r=0;r<4;r++){
        int row = wr*64 + i*16 + g16*4 + r;
        float v = acc[i][j][r];
        if (MODE==2) v = v*(&di4.x)[r] + bias[col];
        if (MODE==3){ v = v + (bias ? bias[col] : 0.f); sj[j]+=v; s2j[j]+=v*v; }
        if (OUTBF) ((ushort*)outv)[(nbase + row)*HID + col] = f2bf(v);
        else       ((float*)outv)[(nbase + row)*HID + col] = v;
      }
    }
  }
  if (MODE==3){
    #pragma unroll
    for (int j=0;j<4;j++){
      float s = sj[j], s2 = s2j[j];
      s  += __shfl_xor(s, 16);  s  += __shfl_xor(s, 32);
      s2 += __shfl_xor(s2,16);  s2 += __shfl_xor(s2,32);
      if (g16==0){
        int col = bn + wc*64 + j*16 + c16;
        atomicAdd(&part[col], s);
        atomicAdd(&part[256+col], s2);
      }
    }
  }
}

// ---------------------------------------------------------------------------
// Elementwise bf16 bn+relu with INLINE stats from atomic sums:
// scl = gamma*rsqrt(var+eps), shf = beta - mean*scl; out = f2bf(relu(in*scl+shf))
// ---------------------------------------------------------------------------
__global__ __launch_bounds__(256) void bnrelu_bf(
    const ushort* __restrict__ in, const float* __restrict__ sums,
    const float* __restrict__ gamma, const float* __restrict__ beta,
    ushort* __restrict__ outp)
{
  size_t i = ((size_t)blockIdx.x*256 + threadIdx.x)*8;
  int c = (int)(i & 255);
  short8 h = *(const short8*)(in + i);
  float4 s0 = *(const float4*)(sums + c);
  float4 s1 = *(const float4*)(sums + c + 4);
  float4 q0 = *(const float4*)(sums + 256 + c);
  float4 q1 = *(const float4*)(sums + 256 + c + 4);
  float4 g0 = *(const float4*)(gamma + c);
  float4 g1 = *(const float4*)(gamma + c + 4);
  float4 b0 = *(const float4*)(beta + c);
  float4 b1 = *(const float4*)(beta + c + 4);
  float ss[8] = {s0.x,s0.y,s0.z,s0.w,s1.x,s1.y,s1.z,s1.w};
  float qq[8] = {q0.x,q0.y,q0.z,q0.w,q1.x,q1.y,q1.z,q1.w};
  float gg[8] = {g0.x,g0.y,g0.z,g0.w,g1.x,g1.y,g1.z,g1.w};
  float bb[8] = {b0.x,b0.y,b0.z,b0.w,b1.x,b1.y,b1.z,b1.w};
  #pragma unroll
  for (int e=0;e<8;e++){
    float mean = ss[e]*BN_INVN;
    float var  = qq[e]*BN_INVN - mean*mean;
    float scl  = gg[e]*rsqrtf(var + 1e-5f);
    float shf  = bb[e] - mean*scl;
    float v = fmaxf(bf2f((ushort)h[e])*scl + shf, 0.f);
    h[e] = (short)f2bf(v);
  }
  *(short8*)(outp + i) = h;
}

// ---------------------------------------------------------------------------
// bf16 MFMA matmul, BM=64 x BN=128 tile; LDS padded to 76.
// out[M,N] = A'[M,K] @ Wt[N,K](bf16) + bias (segmented per 256 cols).
// ATR=1: A' = relu(A*scale+shift).   EPI==1: out = skip + relu(out).
// BNF=1: per-column batch-stat partials atomicAdd into part ({sum,sumsq}[256]).
// TW=1 : permuted bf16 planes (plane[col][node]); rscale[row] folded pre-round.
// ABF=1: A is bf16 [M][K].   OBF=1: output written bf16.
// SBF=1: skip operand is bf16 (read via bf2f).
// ---------------------------------------------------------------------------
template<int EPI, int ATR, int BNF, int TW, int ABF, int OBF, int SBF>
__global__ __launch_bounds__(256) void mm_bf16(
    const void* __restrict__ A, const ushort* __restrict__ Wt,
    const float* __restrict__ bias, const float* __restrict__ biasB,
    const float* __restrict__ biasC, const void* __restrict__ skip,
    const float* __restrict__ bnst,
    void* __restrict__ out, ushort* __restrict__ twp,
    const float* __restrict__ rscale, float* __restrict__ part,
    int M, int K, int N)
{
  __shared__ ushort Al[64][76];
  __shared__ ushort Bl[128][76];
  const int t = threadIdx.x;
  const int bm = blockIdx.x*64, bn = blockIdx.y*128;
  const int w = t>>6, l = t&63;
  const int c16 = l&15, g16 = l>>4;
  const int ar = t>>2, ac = (t&3)*16;
  const int br = t>>1, bc = (t&1)*32;
  f32x4 acc[4][2];
  #pragma unroll
  for (int i=0;i<4;i++)
    #pragma unroll
    for (int j=0;j<2;j++) acc[i][j] = (f32x4){0.f,0.f,0.f,0.f};

  for (int k0=0; k0<K; k0+=64){
    if (ABF){
      const ushort* apb = (const ushort*)A + (size_t)(bm+ar)*K + k0 + ac;
      short8 p0 = *(const short8*)apb;
      short8 p1 = *(const short8*)(apb + 8);
      if (ATR){
        int cb = k0 + ac;
        float scl[16], shf[16];
        *(float4*)&scl[0]  = *(const float4*)(bnst + cb);
        *(float4*)&scl[4]  = *(const float4*)(bnst + cb + 4);
        *(float4*)&scl[8]  = *(const float4*)(bnst + cb + 8);
        *(float4*)&scl[12] = *(const float4*)(bnst + cb + 12);
        *(float4*)&shf[0]  = *(const float4*)(bnst + 256 + cb);
        *(float4*)&shf[4]  = *(const float4*)(bnst + 256 + cb + 4);
        *(float4*)&shf[8]  = *(const float4*)(bnst + 256 + cb + 8);
        *(float4*)&shf[12] = *(const float4*)(bnst + 256 + cb + 12);
        #pragma unroll
        for (int e=0;e<8;e++){
          float v0 = bf2f((ushort)p0[e]);
          v0 = fmaxf(v0*scl[e] + shf[e], 0.f);
          p0[e] = (short)f2bf(v0);
          float v1 = bf2f((ushort)p1[e]);
          v1 = fmaxf(v1*scl[8+e] + shf[8+e], 0.f);
          p1[e] = (short)f2bf(v1);
        }
      }
      *(short8*)&Al[ar][ac]     = p0;
      *(short8*)&Al[ar][ac + 8] = p1;
    } else {
      const float* ap = (const float*)A + (size_t)(bm+ar)*K + k0 + ac;
      #pragma unroll
      for (int j=0;j<2;j++){
        float4 v0 = *(const float4*)(ap + j*8);
        float4 v1 = *(const float4*)(ap + j*8 + 4);
        if (ATR){
          int cb = k0 + ac + j*8;
          float4 s0 = *(const float4*)(bnst + cb);
          float4 s1 = *(const float4*)(bnst + cb + 4);
          float4 h0 = *(const float4*)(bnst + 256 + cb);
          float4 h1 = *(const float4*)(bnst + 256 + cb + 4);
          v0.x=fmaxf(v0.x*s0.x+h0.x,0.f); v0.y=fmaxf(v0.y*s0.y+h0.y,0.f);
          v0.z=fmaxf(v0.z*s0.z+h0.z,0.f); v0.w=fmaxf(v0.w*s0.w+h0.w,0.f);
          v1.x=fmaxf(v1.x*s1.x+h1.x,0.f); v1.y=fmaxf(v1.y*s1.y+h1.y,0.f);
          v1.z=fmaxf(v1.z*s1.z+h1.z,0.f); v1.w=fmaxf(v1.w*s1.w+h1.w,0.f);
        }
        short8 p;
        p[0]=(short)f2bf(v0.x); p[1]=(short)f2bf(v0.y); p[2]=(short)f2bf(v0.z); p[3]=(short)f2bf(v0.w);
        p[4]=(short)f2bf(v1.x); p[5]=(short)f2bf(v1.y); p[6]=(short)f2bf(v1.z); p[7]=(short)f2bf(v1.w);
        *(short8*)&Al[ar][ac+j*8] = p;
      }
    }
    const ushort* bp = Wt + (size_t)(bn+br)*K + k0 + bc;
    #pragma unroll
    for (int j=0;j<4;j++)
      *(short8*)&Bl[br][bc+j*8] = *(const short8*)(bp + j*8);
    __syncthreads();
    #pragma unroll
    for (int kk=0; kk<64; kk+=32){
      short8 af[4], bf[2];
      #pragma unroll
      for (int i=0;i<4;i++) af[i] = *(short8*)&Al[i*16+c16][kk+g16*8];
      #pragma unroll
      for (int j=0;j<2;j++) bf[j] = *(short8*)&Bl[w*32+j*16+c16][kk+g16*8];
      #pragma unroll
      for (int i=0;i<4;i++)
        #pragma unroll
        for (int j=0;j<2;j++)
          acc[i][j] = __builtin_amdgcn_mfma_f32_16x16x32_bf16(af[i], bf[j], acc[i][j], 0,0,0);
    }
    __syncthreads();
  }

  float sj[2]  = {0.f,0.f};
  float s2j[2] = {0.f,0.f};
  #pragma unroll
  for (int j=0;j<2;j++){
    const int col = bn + w*32 + j*16 + c16;
    const int seg = col >> 8;
    const float* bsel = (seg==0) ? bias : ((seg==1) ? biasB : biasC);
    const float bv = bsel ? bsel[col & 255] : 0.f;
    if (TW){
      short8 h8a, h8b;
      #pragma unroll
      for (int i=0;i<4;i++){
        float4 rs = make_float4(1.f,1.f,1.f,1.f);
        if (rscale) rs = *(const float4*)(rscale + bm + i*16 + g16*4);
        #pragma unroll
        for (int r=0;r<4;r++){
          float v = acc[i][j][r] + bv;
          if (BNF){ sj[j]+=v; s2j[j]+=v*v; }
          float sv = v * (&rs.x)[r];
          ushort hb = f2bf(sv);
          if (i<2) h8a[i*4+r]=(short)hb;
          else     h8b[(i-2)*4+r]=(short)hb;
        }
      }
      ushort* dst = twp + (size_t)col*NTOT + bm + g16*16;
      *(short8*)(dst)     = h8a;
      *(short8*)(dst + 8) = h8b;
    } else {
      #pragma unroll
      for (int i=0;i<4;i++){
        #pragma unroll
        for (int r=0;r<4;r++){
          int row = bm + i*16 + g16*4 + r;
          float v = acc[i][j][r] + bv;
          if (BNF){ sj[j]+=v; s2j[j]+=v*v; }
          if (EPI==1){
            float sk = SBF ? bf2f(((const ushort*)skip)[(size_t)row*N+col])
                           : ((const float*)skip)[(size_t)row*N+col];
            v = sk + fmaxf(v,0.f);
          }
          if (OBF) ((ushort*)out)[(size_t)row*N+col] = f2bf(v);
          else     ((float*)out)[(size_t)row*N+col] = v;
        }
      }
    }
  }
  if (BNF){
    #pragma unroll
    for (int j=0;j<2;j++){
      float s = sj[j], s2 = s2j[j];
      s  += __shfl_xor(s, 16);  s  += __shfl_xor(s, 32);
      s2 += __shfl_xor(s2,16);  s2 += __shfl_xor(s2,32);
      if (g16==0){
        int col = bn + w*32 + j*16 + c16;
        atomicAdd(&part[col], s);
        atomicAdd(&part[256+col], s2);
      }
    }
  }
}

// ---------------------------------------------------------------------------
// MFMA attention. Block=(graph,head), 4 waves.
// KVBF=1: K/V bf16.  QBF=1: Q bf16.  OBF=1: O written bf16.
// ---------------------------------------------------------------------------
template<int KVBF, int QBF, int OBF>
__global__ __launch_bounds__(256) void attn_mfma(
    const void* __restrict__ Qpv, const void* __restrict__ Kdv, const void* __restrict__ Vdv,
    void* __restrict__ Ov, int qlen, int klen, int qgstride, int qstride, int kvstride)
{
  __shared__ ushort Kbf[128*72];
  __shared__ ushort Vt[64*136];
  __shared__ ushort Pws[4][16*136];
  int g = blockIdx.x, h = blockIdx.y;
  int hd0 = h*DH;
  int t = threadIdx.x, w = t>>6, l = t&63;

  for (int idx=t; idx<128*16; idx+=256){
    int k = idx>>4, d4 = (idx&15)*4;
    ushort4 kb = make_ushort4(0,0,0,0), vb = kb;
    if (k < klen){
      if (KVBF){
        const ushort* Kd = (const ushort*)Kdv;
        const ushort* Vd = (const ushort*)Vdv;
        kb = *(const ushort4*)(Kd + ((size_t)g*klen + k)*kvstride + hd0 + d4);
        vb = *(const ushort4*)(Vd + ((size_t)g*klen + k)*kvstride + hd0 + d4);
      } else {
        const float* Kd = (const float*)Kdv;
        const float* Vd = (const float*)Vdv;
        float4 kv = *(const float4*)(Kd + ((size_t)g*klen + k)*kvstride + hd0 + d4);
        float4 vv = *(const float4*)(Vd + ((size_t)g*klen + k)*kvstride + hd0 + d4);
        kb = make_ushort4(f2bf(kv.x), f2bf(kv.y), f2bf(kv.z), f2bf(kv.w));
        vb = make_ushort4(f2bf(vv.x), f2bf(vv.y), f2bf(vv.z), f2bf(vv.w));
      }
    }
    *(ushort4*)&Kbf[k*72 + d4] = kb;
    Vt[(d4+0)*136 + k] = vb.x;
    Vt[(d4+1)*136 + k] = vb.y;
    Vt[(d4+2)*136 + k] = vb.z;
    Vt[(d4+3)*136 + k] = vb.w;
  }
  __syncthreads();

  const int c16 = l & 15, g16 = l >> 4;
  const float scl = 1.0f/16.0f;
  int qtiles = (qlen + 15) >> 4;
  for (int qt = w; qt < qtiles; qt += 4){
    int qbase = qt*16;
    int qrow = qbase + c16; if (qrow > qlen-1) qrow = qlen-1;
    short8 qa[2];
    if (QBF){
      const ushort* qr = (const ushort*)Qpv + (size_t)g*qgstride + (size_t)qrow*qstride + hd0 + g16*8;
      qa[0] = *(const short8*)(qr);
      qa[1] = *(const short8*)(qr + 32);
    } else {
      const float* qr = (const float*)Qpv + (size_t)g*qgstride + (size_t)qrow*qstride + hd0 + g16*8;
      #pragma unroll
      for (int dh=0; dh<2; dh++){
        float4 x0 = *(const float4*)(qr + dh*32);
        float4 x1 = *(const float4*)(qr + dh*32 + 4);
        short8 f;
        f[0]=(short)f2bf(x0.x); f[1]=(short)f2bf(x0.y); f[2]=(short)f2bf(x0.z); f[3]=(short)f2bf(x0.w);
        f[4]=(short)f2bf(x1.x); f[5]=(short)f2bf(x1.y); f[6]=(short)f2bf(x1.z); f[7]=(short)f2bf(x1.w);
        qa[dh]=f;
      }
    }
    float p[8][4];
    #pragma unroll
    for (int kt=0; kt<8; kt++){
      f32x4 a = {0.f,0.f,0.f,0.f};
      short8 b0 = *(short8*)&Kbf[(kt*16+c16)*72 + g16*8];
      short8 b1 = *(short8*)&Kbf[(kt*16+c16)*72 + 32 + g16*8];
      a = __builtin_amdgcn_mfma_f32_16x16x32_bf16(qa[0], b0, a, 0,0,0);
      a = __builtin_amdgcn_mfma_f32_16x16x32_bf16(qa[1], b1, a, 0,0,0);
      int k = kt*16 + c16;
      #pragma unroll
      for (int r=0; r<4; r++) p[kt][r] = (k < klen) ? a[r]*scl : -1e30f;
    }
    float m[4], sum[4];
    #pragma unroll
    for (int r=0; r<4; r++){
      float mm = p[0][r];
      #pragma unroll
      for (int kt=1; kt<8; kt++) mm = fmaxf(mm, p[kt][r]);
      for (int o=1; o<16; o<<=1) mm = fmaxf(mm, __shfl_xor(mm, o));
      m[r] = mm;
    }
    #pragma unroll
    for (int r=0; r<4; r++){
      float s = 0.f;
      #pragma unroll
      for (int kt=0; kt<8; kt++){ p[kt][r] = __expf(p[kt][r]-m[r]); s += p[kt][r]; }
      for (int o=1; o<16; o<<=1) s += __shfl_xor(s, o);
      sum[r] = 1.0f/s;
    }
    #pragma unroll
    for (int kt=0; kt<8; kt++)
      #pragma unroll
      for (int r=0; r<4; r++)
        Pws[w][(g16*4+r)*136 + kt*16 + c16] = f2bf(p[kt][r]*sum[r]);
    #pragma unroll
    for (int dt=0; dt<4; dt++){
      f32x4 o4 = {0.f,0.f,0.f,0.f};
      #pragma unroll
      for (int ks=0; ks<4; ks++){
        short8 pa = *(short8*)&Pws[w][c16*136 + ks*32 + g16*8];
        short8 vb = *(short8*)&Vt[(dt*16+c16)*136 + ks*32 + g16*8];
        o4 = __builtin_amdgcn_mfma_f32_16x16x32_bf16(pa, vb, o4, 0,0,0);
      }
      #pragma unroll
      for (int r=0; r<4; r++){
        int q2 = qbase + g16*4 + r;
        if (q2 < qlen){
          int col = hd0 + dt*16 + c16;
          float qv;
          if (QBF) qv = bf2f(((const ushort*)Qpv)[(size_t)g*qgstride + (size_t)q2*qstride + col]);
          else     qv = ((const float*)Qpv)[(size_t)g*qgstride + (size_t)q2*qstride + col];
          float ov = qv + o4[r];
          if (OBF) ((ushort*)Ov)[((size_t)g*qlen + q2)*HID + col] = f2bf(ov);
          else     ((float*)Ov)[((size_t)g*qlen + q2)*HID + col] = ov;
        }
      }
    }
  }
}

// ---------------------------------------------------------------------------
extern "C" void kernel_launch(void* const* d_in, const int* in_sizes, int n_in,
                              void* d_out, int out_size, void* d_ws, size_t ws_size,
                              hipStream_t stream)
{
  (void)in_sizes; (void)n_in; (void)out_size; (void)ws_size;
  const float* x      = (const float*)d_in[0];
  const int*   ei     = (const int*)d_in[1];
  const float* g0_W1=(const float*)d_in[3],  *g0_b1=(const float*)d_in[4],  *g0_ga1=(const float*)d_in[5],  *g0_be1=(const float*)d_in[6];
  const float* g0_W2=(const float*)d_in[7],  *g0_b2=(const float*)d_in[8],  *g0_ga2=(const float*)d_in[9],  *g0_be2=(const float*)d_in[10];
  const float* g1_W1=(const float*)d_in[11], *g1_b1=(const float*)d_in[12], *g1_ga1=(const float*)d_in[13], *g1_be1=(const float*)d_in[14];
  const float* g1_W2=(const float*)d_in[15], *g1_b2=(const float*)d_in[16], *g1_ga2=(const float*)d_in[17], *g1_be2=(const float*)d_in[18];
  const float* lin1_W=(const float*)d_in[19], *lin1_b=(const float*)d_in[20];
  const float* S1=(const float*)d_in[21];
  const float* p1_Wq=(const float*)d_in[22], *p1_Wk=(const float*)d_in[23], *p1_Wv=(const float*)d_in[24], *p1_Wo=(const float*)d_in[25];
  const float* p1_bq=(const float*)d_in[26], *p1_bk=(const float*)d_in[27], *p1_bv=(const float*)d_in[28], *p1_bo=(const float*)d_in[29];
  const float* s2_Wq=(const float*)d_in[30], *s2_Wk=(const float*)d_in[31], *s2_Wv=(const float*)d_in[32], *s2_Wo=(const float*)d_in[33];
  const float* s2_bq=(const float*)d_in[34], *s2_bk=(const float*)d_in[35], *s2_bv=(const float*)d_in[36], *s2_bo=(const float*)d_in[37];
  const float* p3_Wq=(const float*)d_in[38], *p3_Wk=(const float*)d_in[39], *p3_Wv=(const float*)d_in[40], *p3_Wo=(const float*)d_in[41];
  const float* p3_bq=(const float*)d_in[42], *p3_bk=(const float*)d_in[43], *p3_bv=(const float*)d_in[44], *p3_bo=(const float*)d_in[45];
  const float* S3=(const float*)d_in[46];
  const float* lin2_W=(const float*)d_in[47], *lin2_b=(const float*)d_in[48];

  const int* src = ei;
  const int* dst = ei + EDGES;

  // workspace layout (~147 MB)
  float* F = (float*)d_ws;
  const size_t SZ = (size_t)NTOT*HID;              // 8388608 floats
  float* R0=F, *R1=F+SZ, *R2=F+2*SZ, *R3=F+3*SZ;
  float* part  = F + 4*SZ;           // 2048 used: 4 BN atomic-sum buffers x 512
  float* stats = part + 262144;      // (unused, kept for layout stability)
  float* dinv  = stats + 512;        // 32768
  float* qp1   = dinv + 32768;       // 19200
  float* qp3   = qp1 + 19200;        // 256
  float* bcomb = qp3 + 256;          // 512 (combined lin1+KV bias)
  float* o3    = bcomb + 512;        // 65536 (bf16 O3 fits in first half)
  float* xf    = o3 + 65536;         // 65536
  float* tmpKV = xf + 65536;         // 131072 (2x 256x256 fp32 scratch)
  ushort* adjg = (ushort*)(tmpKV + 131072);        // GG*16384 bf16 = 8.39 MB
  ushort* wtb  = adjg + (size_t)GG*NN*NN;          // 16*65536 bf16

  float* bns0 = part;        // g0 bn1
  float* bns1 = part + 512;  // g0 bn2
  float* bns2 = part + 1024; // g1 bn1
  float* bns3 = part + 1536; // g1 bn2

  const dim3 B256(256);
  const dim3 mmBig(512,2), mmMid(300,2);
  #define WT(i) (wtb + (size_t)(i)*65536)

  // --- FAT PREP: weights, adjacency, lin1-fold matmuls, comb bias, qp1, qp3,
  //     and zeroing of the BN atomic-sum buffers ---
  PrepArgs pa;
  pa.e[0]  = {g0_W1, 128, 256};
  pa.e[1]  = {g0_W2, 256, 256};
  pa.e[2]  = {g1_W1, 256, 256};
  pa.e[3]  = {g1_W2, 256, 256};
  pa.e[4]  = {lin1_W,256, 256};
  pa.e[5]  = {p1_Wk, 256, 256};
  pa.e[6]  = {p1_Wv, 256, 256};
  pa.e[7]  = {p1_Wo, 256, 256};
  pa.e[8]  = {s2_Wk, 256, 256};
  pa.e[9]  = {s2_Wv, 256, 256};
  pa.e[10] = {s2_Wq, 256, 256};
  pa.e[11] = {s2_Wo, 256, 256};
  pa.e[12] = {p3_Wk, 256, 256};
  pa.e[13] = {p3_Wv, 256, 256};
  pa.e[14] = {p3_Wo, 256, 256};
  pa.e[15] = {lin2_W,256, 128};
  float* tmpK = tmpKV;
  float* tmpV = tmpKV + 65536;
  fat_prep<<<dim3(559),B256,0,stream>>>(pa, wtb, src, dst, adjg, dinv,
      lin1_W, p1_Wk, p1_Wv, lin1_b, bcomb, tmpK, tmpV,
      S1, p1_Wq, p1_bq, qp1, S3, p3_Wq, p3_bq, qp3, part);
  {
    PrepArgs pc;
    pc.e[0] = {tmpK, 256, 256};
    pc.e[1] = {tmpV, 256, 256};
    prep_weights<<<dim3(2,16),B256,0,stream>>>(pc, WT(5));
  }

  // --- GIN layer 0 (reassociated: h1 = Adj@(x@W1) + b1) ---
  mm_bf16<0,0,0,1,0,0,0><<<mmBig,B256,0,stream>>>(x, WT(0), nullptr,nullptr,nullptr, nullptr, nullptr, nullptr, (ushort*)R1, nullptr, nullptr, NTOT,128,HID); // x@W1 planes -> R1
  agg_gemm<3,1><<<dim3(GG,2),B256,0,stream>>>(adjg, (ushort*)R1, nullptr, nullptr, g0_b1, nullptr, R0, nullptr, bns0); // h1 bf16 -> R0 (+atomic bn sums)
  // h1'' = relu(bn1(h1)) with inline stats; then W2 GEMM -> planes + bn sums
  bnrelu_bf<<<dim3(4096),B256,0,stream>>>((ushort*)R0, bns0, g0_ga1, g0_be1, (ushort*)R3);
  mm_bf16<0,0,1,1,1,0,0><<<mmBig,B256,0,stream>>>(R3, WT(1), g0_b2, nullptr,nullptr, nullptr, nullptr, nullptr, (ushort*)R2, nullptr, bns1, NTOT,256,HID);

  // --- GIN layer 1 (bn2+outer-relu of layer0 fused at plane load, inline stats) ---
  agg_gemm<1,1><<<dim3(GG,2),B256,0,stream>>>(adjg, (ushort*)R2, nullptr, bns1, g0_ga2, g0_be2, R0, nullptr, nullptr); // h1' bf16 -> R0
  mm_bf16<0,0,1,0,1,1,0><<<mmBig,B256,0,stream>>>(R0, WT(2), g1_b1, nullptr,nullptr, nullptr, nullptr, R1, nullptr, nullptr, bns2, NTOT,256,HID); // bf16 -> R1
  bnrelu_bf<<<dim3(4096),B256,0,stream>>>((ushort*)R1, bns2, g1_ga1, g1_be1, (ushort*)R3);
  mm_bf16<0,0,1,0,1,1,0><<<mmBig,B256,0,stream>>>(R3, WT(3), g1_b2, nullptr,nullptr, nullptr, nullptr, R2, nullptr, nullptr, bns3, NTOT,256,HID); // h2' bf16 -> R2

  // --- h2'' = relu(bn2'(h2')) materialized once (inline stats) ---
  bnrelu_bf<<<dim3(4096),B256,0,stream>>>((ushort*)R2, bns3, g1_ga2, g1_be2, (ushort*)R1);

  // --- GMPool_G (p1): K,V planes from h2'' via folded lin1+KV weights ---
  mm_bf16<0,0,0,1,1,0,0><<<dim3(512,4),B256,0,stream>>>(R1, WT(5), bcomb, bcomb+256, nullptr, nullptr, nullptr, nullptr, (ushort*)R0, dinv, nullptr, NTOT,256,512);
  {
    void* Kb = (void*)R3;
    void* Vb = (void*)((ushort*)R3 + (size_t)NTOT*HID);
    agg_gemm<2,1><<<dim3(GG,4),B256,0,stream>>>(adjg, (ushort*)R0, (ushort*)R0 + (size_t)256*NTOT, dinv, p1_bk, p1_bv, Kb, Vb, nullptr); // bf16 Kd,Vd -> R3
    attn_mfma<1,0,1><<<dim3(GG,4),B256,0,stream>>>(qp1, Kb, Vb, (void*)R2, 75,128, 0, HID, HID);  // O1 bf16 -> R2
  }
  mm_bf16<1,0,0,0,1,1,1><<<mmMid,B256,0,stream>>>(R2, WT(7), p1_bo, nullptr,nullptr, R2, nullptr, R1, nullptr, nullptr, nullptr, 19200,256,HID); // Xp bf16 -> R1

  // --- SelfAtt (s2): ONE fused K|V|Q GEMM (N=768, all bf16 out) ---
  {
    ushort* KVQ = (ushort*)R0;                       // [19200][768] bf16 (29.5 MB)
    mm_bf16<0,0,0,0,1,1,0><<<dim3(300,6),B256,0,stream>>>(R1, WT(8), s2_bk, s2_bv, s2_bq, nullptr, nullptr, KVQ, nullptr, nullptr, nullptr, 19200,256,768);
    attn_mfma<1,1,1><<<dim3(GG,4),B256,0,stream>>>((const void*)(KVQ+512), (const void*)KVQ, (const void*)(KVQ+256), (void*)R3, 75,75, 75*768, 768, 768); // O2 bf16 -> R3
  }
  mm_bf16<1,0,0,0,1,1,1><<<mmMid,B256,0,stream>>>(R3, WT(11), s2_bo, nullptr,nullptr, R3, nullptr, R1, nullptr, nullptr, nullptr, 19200,256,HID); // Xp2 bf16 -> R1

  // --- GMPool_I (p3): fused K|V GEMM (bf16 A, N=512, bf16 out) ---
  {
    ushort* KV3 = (ushort*)R2;                       // [19200][512] bf16
    mm_bf16<0,0,0,0,1,1,0><<<dim3(300,4),B256,0,stream>>>(R1, WT(12), p3_bk, p3_bv, nullptr, nullptr, nullptr, KV3, nullptr, nullptr, nullptr, 19200,256,512);
    attn_mfma<1,0,1><<<dim3(GG,4),B256,0,stream>>>(qp3, (const void*)KV3, (const void*)(KV3+256), (void*)o3, 1,75, 0, HID, 512); // O3 bf16 -> o3
  }
  mm_bf16<1,0,0,0,1,1,1><<<dim3(4,2),B256,0,stream>>>(o3, WT(14), p3_bo, nullptr,nullptr, o3, nullptr, xf, nullptr, nullptr, nullptr, 256,256,HID); // xf bf16

  // --- lin2 ---
  mm_bf16<0,0,0,0,1,0,0><<<dim3(4,1),B256,0,stream>>>(xf, WT(15), lin2_b, nullptr,nullptr, nullptr, nullptr, (float*)d_out, nullptr, nullptr, nullptr, 256,256,128);
}

// Round 17
// 330.391 us; speedup vs baseline: 1.1353x; 1.1353x over previous
//
#include <hip/hip_runtime.h>
#include <math.h>

// Problem constants
#define GG 256            // graphs
#define NN 128            // nodes per graph
#define NTOT (GG*NN)      // 32768
#define EPG 2048          // edges per graph (N*DEG)
#define EDGES (GG*EPG)    // 524288
#define HID 256
#define DH 64             // head dim (HID/4)

typedef __attribute__((ext_vector_type(8))) short short8;
typedef __attribute__((ext_vector_type(4))) float f32x4;

__device__ __forceinline__ ushort f2bf(float f){
  union { float f; unsigned u; } x; x.f = f;
  unsigned r = x.u + 0x7fffu + ((x.u >> 16) & 1u);   // RNE
  return (ushort)(r >> 16);
}
__device__ __forceinline__ float bf2f(ushort h){
  union { unsigned u; float f; } x; x.u = ((unsigned)h) << 16;
  return x.f;
}
// Node permutation within each 64-row block: plane position p holds row R(p).
__device__ __forceinline__ int permR(int p){
  return ((p>>2)&3)*16 + ((p>>4)&3)*4 + (p&3) + (p&64);
}

// ---------------------------------------------------------------------------
// Shared inline bodies for the fat prep kernel
// ---------------------------------------------------------------------------
struct PrepW { const float* w; int K; int N; };
struct PrepArgs { PrepW e[16]; };

// fp32 W[K,N] -> bf16 Wt[N,K], one 64x64 tile (whole block participates)
__device__ __forceinline__ void prepw_body(char* smem, const float* W, int K, int N,
                                           ushort* out, int tk, int tn)
{
  ushort (*T)[72] = (ushort (*)[72])smem;
  int t = threadIdx.x;
  int kr = t>>2, n0 = (t&3)*16;
  #pragma unroll
  for (int j=0;j<4;j++){
    float4 v = *(const float4*)(W + (size_t)(tk*64+kr)*N + tn*64 + n0 + j*4);
    T[n0+j*4+0][kr] = f2bf(v.x);
    T[n0+j*4+1][kr] = f2bf(v.y);
    T[n0+j*4+2][kr] = f2bf(v.z);
    T[n0+j*4+3][kr] = f2bf(v.w);
  }
  __syncthreads();
  int nr = t>>2, k0 = (t&3)*16;
  *(short8*)(out + (size_t)(tn*64+nr)*K + tk*64 + k0)     = *(short8*)&T[nr][k0];
  *(short8*)(out + (size_t)(tn*64+nr)*K + tk*64 + k0 + 8) = *(short8*)&T[nr][k0+8];
}

// fp32 tiled matmul 64x64 tile: out[M,N] = A[M,K]@W[K,N] + bias
__device__ __forceinline__ void mmk_body(char* smem, const float* A, const float* W,
    const float* bias, float* out, int bm, int bn, int M, int K, int N)
{
  float (*As)[68] = (float (*)[68])smem;              // [16][68]
  float (*Ws)[68] = (float (*)[68])(smem + 16*68*4);  // [16][68]
  const int t  = threadIdx.x;
  const int tx = t & 15, ty = t >> 4;
  const int lrow = t >> 2;
  const int lkc  = (t & 3) * 4;
  const int wkr  = t >> 4;
  const int wnc  = (t & 15) * 4;
  float acc[4][4] = {{0.f}};
  for (int k0 = 0; k0 < K; k0 += 16) {
    float4 av = make_float4(0.f,0.f,0.f,0.f);
    if (bm + lrow < M) av = *(const float4*)(A + (size_t)(bm+lrow)*K + k0 + lkc);
    float4 wv = *(const float4*)(W + (size_t)(k0+wkr)*N + bn + wnc);
    As[lkc+0][lrow]=av.x; As[lkc+1][lrow]=av.y; As[lkc+2][lrow]=av.z; As[lkc+3][lrow]=av.w;
    *(float4*)&Ws[wkr][wnc] = wv;
    __syncthreads();
    #pragma unroll
    for (int kk=0; kk<16; kk++){
      float4 a4 = *(float4*)&As[kk][ty*4];
      float4 b4 = *(float4*)&Ws[kk][tx*4];
      acc[0][0]+=a4.x*b4.x; acc[0][1]+=a4.x*b4.y; acc[0][2]+=a4.x*b4.z; acc[0][3]+=a4.x*b4.w;
      acc[1][0]+=a4.y*b4.x; acc[1][1]+=a4.y*b4.y; acc[1][2]+=a4.y*b4.z; acc[1][3]+=a4.y*b4.w;
      acc[2][0]+=a4.z*b4.x; acc[2][1]+=a4.z*b4.y; acc[2][2]+=a4.z*b4.z; acc[2][3]+=a4.z*b4.w;
      acc[3][0]+=a4.w*b4.x; acc[3][1]+=a4.w*b4.y; acc[3][2]+=a4.w*b4.z; acc[3][3]+=a4.w*b4.w;
    }
    __syncthreads();
  }
  #pragma unroll
  for (int i=0;i<4;i++){
    int r = bm + ty*4 + i;
    if (r >= M) continue;
    #pragma unroll
    for (int j=0;j<4;j++){
      int c = bn + tx*4 + j;
      float v = acc[i][j] + (bias ? bias[c] : 0.f);
      out[(size_t)r*N + c] = v;
    }
  }
}

// ---------------------------------------------------------------------------
// FAT PREP: one dispatch for all input-only work.
// blocks [0,256)  : prep_weights (16 weights x 16 tiles)
// blocks [256,512): adj_build (256 graphs)
// blocks [512,528): tmpK = lin1_W @ p1_Wk   (4x4 tiles)
// blocks [528,544): tmpV = lin1_W @ p1_Wv
// blocks [544,546): comb_bias
// blocks [546,554): qp1 = S1@p1_Wq + bq   (75x256, 2x4 tiles)
// blocks [554,558): qp3 = S3@p3_Wq + bq   (1x256, 1x4 tiles)
// ---------------------------------------------------------------------------
__global__ __launch_bounds__(256) void fat_prep(
    PrepArgs pa, ushort* __restrict__ wtb,
    const int* __restrict__ src, const int* __restrict__ dst,
    ushort* __restrict__ adjg, float* __restrict__ dinv,
    const float* lin1_W, const float* p1_Wk, const float* p1_Wv,
    const float* lin1_b, float* bcomb, float* tmpK, float* tmpV,
    const float* S1, const float* p1_Wq, const float* p1_bq, float* qp1,
    const float* S3, const float* p3_Wq, const float* p3_bq, float* qp3)
{
  __shared__ char smem[65536];
  const int b = blockIdx.x;
  const int t = threadIdx.x;

  if (b < 256){
    int wi = b>>4, tile = b&15;
    const float* W = pa.e[wi].w;
    int K = pa.e[wi].K, N = pa.e[wi].N;
    int tk_n = K>>6, tn_n = N>>6;
    if (tile >= tk_n*tn_n) return;
    prepw_body(smem, W, K, N, wtb + (size_t)wi*65536, tile % tk_n, tile / tk_n);
  } else if (b < 512){
    int g = b - 256;
    unsigned* hist = (unsigned*)smem;               // [NN*NN] 64KB
    int base = g*EPG, nb = g*NN;
    for (int i=t; i<NN*NN; i+=256) hist[i]=0u;
    __syncthreads();
    {
      int4 a = *(const int4*)(src + base + t*8);
      int4 bb = *(const int4*)(src + base + t*8 + 4);
      int4 c = *(const int4*)(dst + base + t*8);
      int4 d = *(const int4*)(dst + base + t*8 + 4);
      atomicAdd(&hist[(a.x-nb)*NN + (c.x-nb)], 1u);
      atomicAdd(&hist[(a.y-nb)*NN + (c.y-nb)], 1u);
      atomicAdd(&hist[(a.z-nb)*NN + (c.z-nb)], 1u);
      atomicAdd(&hist[(a.w-nb)*NN + (c.w-nb)], 1u);
      atomicAdd(&hist[(bb.x-nb)*NN + (d.x-nb)], 1u);
      atomicAdd(&hist[(bb.y-nb)*NN + (d.y-nb)], 1u);
      atomicAdd(&hist[(bb.z-nb)*NN + (d.z-nb)], 1u);
      atomicAdd(&hist[(bb.w-nb)*NN + (d.w-nb)], 1u);
    }
    __syncthreads();
    if (t < NN){
      unsigned dg = 0;
      for (int k=0; k<NN; k++) dg += hist[k*NN + t];
      dinv[nb + t] = rsqrtf((float)dg + 1.0f);
    }
    __syncthreads();
    ushort* out = adjg + (size_t)g*NN*NN;
    for (int idx=t; idx<NN*NN; idx+=256){
      int i = idx >> 7, kp = idx & 127;
      int j = permR(kp);
      unsigned cnt = hist[j*NN + i];
      float v = (float)cnt + ((i==j) ? 1.0f : 0.0f);
      out[idx] = f2bf(v);
    }
  } else if (b < 528){
    int idx = b - 512;
    mmk_body(smem, lin1_W, p1_Wk, nullptr, tmpK, (idx&3)*64, (idx>>2)*64, 256,256,256);
  } else if (b < 544){
    int idx = b - 528;
    mmk_body(smem, lin1_W, p1_Wv, nullptr, tmpV, (idx&3)*64, (idx>>2)*64, 256,256,256);
  } else if (b < 546){
    int sel = b - 544;
    const float* W = sel ? p1_Wv : p1_Wk;
    float s = 0.f;
    for (int k=0;k<256;k++) s += lin1_b[k]*W[k*256+t];
    bcomb[sel*256+t] = s;
  } else if (b < 554){
    int idx = b - 546;                               // (2,4): bx=idx&1, by=idx>>1
    mmk_body(smem, S1, p1_Wq, p1_bq, qp1, (idx&1)*64, (idx>>1)*64, 75,256,HID);
  } else {
    int idx = b - 554;                               // (1,4)
    mmk_body(smem, S3, p3_Wq, p3_bq, qp3, 0, idx*64, 1,256,HID);
  }
}

// ---------------------------------------------------------------------------
// Weight prep standalone (for the folded lin1+KV weights, after fat_prep)
// ---------------------------------------------------------------------------
__global__ __launch_bounds__(256) void prep_weights(PrepArgs pa, ushort* __restrict__ wtb)
{
  __shared__ char smem[9216];
  int wi = blockIdx.x;
  const float* W = pa.e[wi].w;
  int K = pa.e[wi].K, N = pa.e[wi].N;
  int tk_n = K>>6, tn_n = N>>6;
  int tile = blockIdx.y;
  if (tile >= tk_n*tn_n) return;
  prepw_body(smem, W, K, N, wtb + (size_t)wi*65536, tile % tk_n, tile / tk_n);
}

// ---------------------------------------------------------------------------
// LDS-free dense aggregation: out[128][256] = Adj[128x128] @ X (per graph).
// B read from permuted bf16 planes (plane[col][node], NTOT per column).
// MODE 1: GIN-1, f = relu(v*scl+shf), transform at load.
// MODE 2: GCN, planes hold xw*dinv_j; epilogue v = v*dinv_i + bias.
// MODE 3: GIN-0 (reassociated): plain agg + bias + fused BN partials.
// OUTBF=1: write bf16 (f2bf(v)).
// ---------------------------------------------------------------------------
template<int MODE, int OUTBF>
__global__ __launch_bounds__(256) void agg_gemm(
    const ushort* __restrict__ adjg,
    const ushort* __restrict__ P0, const ushort* __restrict__ P1,
    const float* __restrict__ aux,       // stats (MODE1) or dinv (MODE2)
    const float* __restrict__ b0, const float* __restrict__ b1,
    void* __restrict__ out0v, void* __restrict__ out1v,
    float* __restrict__ part)
{
  const int g = blockIdx.x;
  int bn, sel = 0;
  if (MODE==2){ sel = blockIdx.y >> 1; bn = (blockIdx.y & 1)*128; }
  else bn = blockIdx.y*128;
  const ushort* Ph = (MODE==2 && sel) ? P1 : P0;
  const float* bias = (MODE==2) ? (sel ? b1 : b0) : b0;
  void* outv = (MODE==2 && sel) ? out1v : out0v;
  const int t = threadIdx.x;
  const int w = t>>6, l = t&63;
  const int wr = w>>1, wc = w&1;
  const int c16 = l&15, g16 = l>>4;
  const size_t nbase = (size_t)g*NN;
  f32x4 acc[4][4];
  #pragma unroll
  for (int i=0;i<4;i++)
    #pragma unroll
    for (int j=0;j<4;j++) acc[i][j] = (f32x4){0.f,0.f,0.f,0.f};
  const ushort* ag = adjg + (size_t)g*NN*NN;

  float sclj[4], shfj[4];
  if (MODE==1){
    #pragma unroll
    for (int j=0;j<4;j++){
      int col = bn + wc*64 + j*16 + c16;
      sclj[j] = aux[col]; shfj[j] = aux[256+col];
    }
  }

  for (int kk=0; kk<128; kk+=32){
    short8 af[4];
    #pragma unroll
    for (int i=0;i<4;i++)
      af[i] = *(const short8*)(ag + (wr*64+i*16+c16)*NN + kk + g16*8);
    short8 bh[4];
    size_t off = nbase + kk + g16*8;
    #pragma unroll
    for (int j=0;j<4;j++){
      int col = bn + wc*64 + j*16 + c16;
      short8 h8 = *(const short8*)(Ph + (size_t)col*NTOT + off);
      if (MODE==1){
        #pragma unroll
        for (int e=0;e<8;e++){
          float v = bf2f((ushort)h8[e]);
          v = fmaxf(v*sclj[j] + shfj[j], 0.f);
          h8[e] = (short)f2bf(v);
        }
      }
      bh[j] = h8;
    }
    #pragma unroll
    for (int i=0;i<4;i++)
      #pragma unroll
      for (int j=0;j<4;j++)
        acc[i][j] = __builtin_amdgcn_mfma_f32_16x16x32_bf16(af[i], bh[j], acc[i][j], 0,0,0);
  }
  float sj[4]  = {0.f,0.f,0.f,0.f};
  float s2j[4] = {0.f,0.f,0.f,0.f};
  #pragma unroll
  for (int i=0;i<4;i++){
    float4 di4 = make_float4(1.f,1.f,1.f,1.f);
    if (MODE==2) di4 = *(const float4*)(aux + nbase + wr*64 + i*16 + g16*4);
    #pragma unroll
    for (int j=0;j<4;j++){
      int col = bn + wc*64 + j*16 + c16;
      #pragma unroll
      for (int r=0;r<4;r++){
        int row = wr*64 + i*16 + g16*4 + r;
        float v = acc[i][j][r];
        if (MODE==2) v = v*(&di4.x)[r] + bias[col];
        if (MODE==3){ v = v + (bias ? bias[col] : 0.f); sj[j]+=v; s2j[j]+=v*v; }
        if (OUTBF) ((ushort*)outv)[(nbase + row)*HID + col] = f2bf(v);
        else       ((float*)outv)[(nbase + row)*HID + col] = v;
      }
    }
  }
  if (MODE==3){
    #pragma unroll
    for (int j=0;j<4;j++){
      float s = sj[j], s2 = s2j[j];
      s  += __shfl_xor(s, 16);  s  += __shfl_xor(s, 32);
      s2 += __shfl_xor(s2,16);  s2 += __shfl_xor(s2,32);
      if (g16==0){
        int col = bn + wc*64 + j*16 + c16;
        part[(g*2+wr)*256 + col]          = s;
        part[131072 + (g*2+wr)*256 + col] = s2;
      }
    }
  }
}

// ---------------------------------------------------------------------------
// Elementwise bf16 bn+relu: out = f2bf(relu(bf2f(in)*scl + shf)), [node][256].
// ---------------------------------------------------------------------------
__global__ __launch_bounds__(256) void bnrelu_bf(
    const ushort* __restrict__ in, const float* __restrict__ stats,
    ushort* __restrict__ outp)
{
  size_t i = ((size_t)blockIdx.x*256 + threadIdx.x)*8;
  int c = (int)(i & 255);
  short8 h = *(const short8*)(in + i);
  float4 s0 = *(const float4*)(stats + c);
  float4 s1 = *(const float4*)(stats + c + 4);
  float4 h0 = *(const float4*)(stats + 256 + c);
  float4 h1 = *(const float4*)(stats + 256 + c + 4);
  float sc[8] = {s0.x,s0.y,s0.z,s0.w,s1.x,s1.y,s1.z,s1.w};
  float sh[8] = {h0.x,h0.y,h0.z,h0.w,h1.x,h1.y,h1.z,h1.w};
  #pragma unroll
  for (int e=0;e<8;e++){
    float v = fmaxf(bf2f((ushort)h[e])*sc[e] + sh[e], 0.f);
    h[e] = (short)f2bf(v);
  }
  *(short8*)(outp + i) = h;
}

// ---------------------------------------------------------------------------
// BatchNorm stats finalize, PARALLEL: one column per block (256 blocks).
// ---------------------------------------------------------------------------
__global__ __launch_bounds__(256) void bn_final2(const float* __restrict__ part,
    const float* __restrict__ gamma, const float* __restrict__ beta, float* __restrict__ stats)
{
  int c = blockIdx.x, t = threadIdx.x;
  float s  = part[(size_t)t*256+c]          + part[(size_t)(t+256)*256+c];
  float s2 = part[131072+(size_t)t*256+c]   + part[131072+(size_t)(t+256)*256+c];
  #pragma unroll
  for (int o=1;o<64;o<<=1){ s += __shfl_xor(s,o); s2 += __shfl_xor(s2,o); }
  __shared__ float ws[8];
  int wv = t>>6;
  if ((t&63)==0){ ws[wv]=s; ws[4+wv]=s2; }
  __syncthreads();
  if (t==0){
    float S  = ws[0]+ws[1]+ws[2]+ws[3];
    float S2 = ws[4]+ws[5]+ws[6]+ws[7];
    const float invn = 1.0f/(float)NTOT;
    float mean = S*invn;
    float var  = S2*invn - mean*mean;
    float scl  = gamma[c]*rsqrtf(var + 1e-5f);
    stats[c]     = scl;
    stats[256+c] = beta[c] - mean*scl;
  }
}

// ---------------------------------------------------------------------------
// bf16 MFMA matmul, BM=64 x BN=128 tile; LDS padded to 76.
// out[M,N] = A'[M,K] @ Wt[N,K](bf16) + bias (segmented per 256 cols).
// ATR=1: A' = relu(A*scale+shift).   EPI==1: out = skip + relu(out).
// BNF=1: per-column batch-stat partials -> part[(bm>>6)*256+col] (s2 +131072).
// TW=1 : permuted bf16 planes (plane[col][node]); rscale[row] folded pre-round.
// ABF=1: A is bf16 [M][K].   OBF=1: output written bf16.
// SBF=1: skip operand is bf16 (read via bf2f).
// ---------------------------------------------------------------------------
template<int EPI, int ATR, int BNF, int TW, int ABF, int OBF, int SBF>
__global__ __launch_bounds__(256) void mm_bf16(
    const void* __restrict__ A, const ushort* __restrict__ Wt,
    const float* __restrict__ bias, const float* __restrict__ biasB,
    const float* __restrict__ biasC, const void* __restrict__ skip,
    const float* __restrict__ bnst,
    void* __restrict__ out, ushort* __restrict__ twp,
    const float* __restrict__ rscale, float* __restrict__ part,
    int M, int K, int N)
{
  __shared__ ushort Al[64][76];
  __shared__ ushort Bl[128][76];
  const int t = threadIdx.x;
  const int bm = blockIdx.x*64, bn = blockIdx.y*128;
  const int w = t>>6, l = t&63;
  const int c16 = l&15, g16 = l>>4;
  const int ar = t>>2, ac = (t&3)*16;
  const int br = t>>1, bc = (t&1)*32;
  f32x4 acc[4][2];
  #pragma unroll
  for (int i=0;i<4;i++)
    #pragma unroll
    for (int j=0;j<2;j++) acc[i][j] = (f32x4){0.f,0.f,0.f,0.f};

  for (int k0=0; k0<K; k0+=64){
    if (ABF){
      const ushort* apb = (const ushort*)A + (size_t)(bm+ar)*K + k0 + ac;
      short8 p0 = *(const short8*)apb;
      short8 p1 = *(const short8*)(apb + 8);
      if (ATR){
        int cb = k0 + ac;
        float scl[16], shf[16];
        *(float4*)&scl[0]  = *(const float4*)(bnst + cb);
        *(float4*)&scl[4]  = *(const float4*)(bnst + cb + 4);
        *(float4*)&scl[8]  = *(const float4*)(bnst + cb + 8);
        *(float4*)&scl[12] = *(const float4*)(bnst + cb + 12);
        *(float4*)&shf[0]  = *(const float4*)(bnst + 256 + cb);
        *(float4*)&shf[4]  = *(const float4*)(bnst + 256 + cb + 4);
        *(float4*)&shf[8]  = *(const float4*)(bnst + 256 + cb + 8);
        *(float4*)&shf[12] = *(const float4*)(bnst + 256 + cb + 12);
        #pragma unroll
        for (int e=0;e<8;e++){
          float v0 = bf2f((ushort)p0[e]);
          v0 = fmaxf(v0*scl[e] + shf[e], 0.f);
          p0[e] = (short)f2bf(v0);
          float v1 = bf2f((ushort)p1[e]);
          v1 = fmaxf(v1*scl[8+e] + shf[8+e], 0.f);
          p1[e] = (short)f2bf(v1);
        }
      }
      *(short8*)&Al[ar][ac]     = p0;
      *(short8*)&Al[ar][ac + 8] = p1;
    } else {
      const float* ap = (const float*)A + (size_t)(bm+ar)*K + k0 + ac;
      #pragma unroll
      for (int j=0;j<2;j++){
        float4 v0 = *(const float4*)(ap + j*8);
        float4 v1 = *(const float4*)(ap + j*8 + 4);
        if (ATR){
          int cb = k0 + ac + j*8;
          float4 s0 = *(const float4*)(bnst + cb);
          float4 s1 = *(const float4*)(bnst + cb + 4);
          float4 h0 = *(const float4*)(bnst + 256 + cb);
          float4 h1 = *(const float4*)(bnst + 256 + cb + 4);
          v0.x=fmaxf(v0.x*s0.x+h0.x,0.f); v0.y=fmaxf(v0.y*s0.y+h0.y,0.f);
          v0.z=fmaxf(v0.z*s0.z+h0.z,0.f); v0.w=fmaxf(v0.w*s0.w+h0.w,0.f);
          v1.x=fmaxf(v1.x*s1.x+h1.x,0.f); v1.y=fmaxf(v1.y*s1.y+h1.y,0.f);
          v1.z=fmaxf(v1.z*s1.z+h1.z,0.f); v1.w=fmaxf(v1.w*s1.w+h1.w,0.f);
        }
        short8 p;
        p[0]=(short)f2bf(v0.x); p[1]=(short)f2bf(v0.y); p[2]=(short)f2bf(v0.z); p[3]=(short)f2bf(v0.w);
        p[4]=(short)f2bf(v1.x); p[5]=(short)f2bf(v1.y); p[6]=(short)f2bf(v1.z); p[7]=(short)f2bf(v1.w);
        *(short8*)&Al[ar][ac+j*8] = p;
      }
    }
    const ushort* bp = Wt + (size_t)(bn+br)*K + k0 + bc;
    #pragma unroll
    for (int j=0;j<4;j++)
      *(short8*)&Bl[br][bc+j*8] = *(const short8*)(bp + j*8);
    __syncthreads();
    #pragma unroll
    for (int kk=0; kk<64; kk+=32){
      short8 af[4], bf[2];
      #pragma unroll
      for (int i=0;i<4;i++) af[i] = *(short8*)&Al[i*16+c16][kk+g16*8];
      #pragma unroll
      for (int j=0;j<2;j++) bf[j] = *(short8*)&Bl[w*32+j*16+c16][kk+g16*8];
      #pragma unroll
      for (int i=0;i<4;i++)
        #pragma unroll
        for (int j=0;j<2;j++)
          acc[i][j] = __builtin_amdgcn_mfma_f32_16x16x32_bf16(af[i], bf[j], acc[i][j], 0,0,0);
    }
    __syncthreads();
  }

  float sj[2]  = {0.f,0.f};
  float s2j[2] = {0.f,0.f};
  #pragma unroll
  for (int j=0;j<2;j++){
    const int col = bn + w*32 + j*16 + c16;
    const int seg = col >> 8;
    const float* bsel = (seg==0) ? bias : ((seg==1) ? biasB : biasC);
    const float bv = bsel ? bsel[col & 255] : 0.f;
    if (TW){
      short8 h8a, h8b;
      #pragma unroll
      for (int i=0;i<4;i++){
        float4 rs = make_float4(1.f,1.f,1.f,1.f);
        if (rscale) rs = *(const float4*)(rscale + bm + i*16 + g16*4);
        #pragma unroll
        for (int r=0;r<4;r++){
          float v = acc[i][j][r] + bv;
          if (BNF){ sj[j]+=v; s2j[j]+=v*v; }
          float sv = v * (&rs.x)[r];
          ushort hb = f2bf(sv);
          if (i<2) h8a[i*4+r]=(short)hb;
          else     h8b[(i-2)*4+r]=(short)hb;
        }
      }
      ushort* dst = twp + (size_t)col*NTOT + bm + g16*16;
      *(short8*)(dst)     = h8a;
      *(short8*)(dst + 8) = h8b;
    } else {
      #pragma unroll
      for (int i=0;i<4;i++){
        #pragma unroll
        for (int r=0;r<4;r++){
          int row = bm + i*16 + g16*4 + r;
          float v = acc[i][j][r] + bv;
          if (BNF){ sj[j]+=v; s2j[j]+=v*v; }
          if (EPI==1){
            float sk = SBF ? bf2f(((const ushort*)skip)[(size_t)row*N+col])
                           : ((const float*)skip)[(size_t)row*N+col];
            v = sk + fmaxf(v,0.f);
          }
          if (OBF) ((ushort*)out)[(size_t)row*N+col] = f2bf(v);
          else     ((float*)out)[(size_t)row*N+col] = v;
        }
      }
    }
  }
  if (BNF){
    #pragma unroll
    for (int j=0;j<2;j++){
      float s = sj[j], s2 = s2j[j];
      s  += __shfl_xor(s, 16);  s  += __shfl_xor(s, 32);
      s2 += __shfl_xor(s2,16);  s2 += __shfl_xor(s2,32);
      if (g16==0){
        int col = bn + w*32 + j*16 + c16;
        part[(bm>>6)*256 + col]          = s;
        part[131072 + (bm>>6)*256 + col] = s2;
      }
    }
  }
}

// ---------------------------------------------------------------------------
// MFMA attention. Block=(graph,head), 4 waves.
// KVBF=1: K/V bf16.  QBF=1: Q bf16.  OBF=1: O written bf16.
// ---------------------------------------------------------------------------
template<int KVBF, int QBF, int OBF>
__global__ __launch_bounds__(256) void attn_mfma(
    const void* __restrict__ Qpv, const void* __restrict__ Kdv, const void* __restrict__ Vdv,
    void* __restrict__ Ov, int qlen, int klen, int qgstride, int qstride, int kvstride)
{
  __shared__ ushort Kbf[128*72];
  __shared__ ushort Vt[64*136];
  __shared__ ushort Pws[4][16*136];
  int g = blockIdx.x, h = blockIdx.y;
  int hd0 = h*DH;
  int t = threadIdx.x, w = t>>6, l = t&63;

  for (int idx=t; idx<128*16; idx+=256){
    int k = idx>>4, d4 = (idx&15)*4;
    ushort4 kb = make_ushort4(0,0,0,0), vb = kb;
    if (k < klen){
      if (KVBF){
        const ushort* Kd = (const ushort*)Kdv;
        const ushort* Vd = (const ushort*)Vdv;
        kb = *(const ushort4*)(Kd + ((size_t)g*klen + k)*kvstride + hd0 + d4);
        vb = *(const ushort4*)(Vd + ((size_t)g*klen + k)*kvstride + hd0 + d4);
      } else {
        const float* Kd = (const float*)Kdv;
        const float* Vd = (const float*)Vdv;
        float4 kv = *(const float4*)(Kd + ((size_t)g*klen + k)*kvstride + hd0 + d4);
        float4 vv = *(const float4*)(Vd + ((size_t)g*klen + k)*kvstride + hd0 + d4);
        kb = make_ushort4(f2bf(kv.x), f2bf(kv.y), f2bf(kv.z), f2bf(kv.w));
        vb = make_ushort4(f2bf(vv.x), f2bf(vv.y), f2bf(vv.z), f2bf(vv.w));
      }
    }
    *(ushort4*)&Kbf[k*72 + d4] = kb;
    Vt[(d4+0)*136 + k] = vb.x;
    Vt[(d4+1)*136 + k] = vb.y;
    Vt[(d4+2)*136 + k] = vb.z;
    Vt[(d4+3)*136 + k] = vb.w;
  }
  __syncthreads();

  const int c16 = l & 15, g16 = l >> 4;
  const float scl = 1.0f/16.0f;
  int qtiles = (qlen + 15) >> 4;
  for (int qt = w; qt < qtiles; qt += 4){
    int qbase = qt*16;
    int qrow = qbase + c16; if (qrow > qlen-1) qrow = qlen-1;
    short8 qa[2];
    if (QBF){
      const ushort* qr = (const ushort*)Qpv + (size_t)g*qgstride + (size_t)qrow*qstride + hd0 + g16*8;
      qa[0] = *(const short8*)(qr);
      qa[1] = *(const short8*)(qr + 32);
    } else {
      const float* qr = (const float*)Qpv + (size_t)g*qgstride + (size_t)qrow*qstride + hd0 + g16*8;
      #pragma unroll
      for (int dh=0; dh<2; dh++){
        float4 x0 = *(const float4*)(qr + dh*32);
        float4 x1 = *(const float4*)(qr + dh*32 + 4);
        short8 f;
        f[0]=(short)f2bf(x0.x); f[1]=(short)f2bf(x0.y); f[2]=(short)f2bf(x0.z); f[3]=(short)f2bf(x0.w);
        f[4]=(short)f2bf(x1.x); f[5]=(short)f2bf(x1.y); f[6]=(short)f2bf(x1.z); f[7]=(short)f2bf(x1.w);
        qa[dh]=f;
      }
    }
    float p[8][4];
    #pragma unroll
    for (int kt=0; kt<8; kt++){
      f32x4 a = {0.f,0.f,0.f,0.f};
      short8 b0 = *(short8*)&Kbf[(kt*16+c16)*72 + g16*8];
      short8 b1 = *(short8*)&Kbf[(kt*16+c16)*72 + 32 + g16*8];
      a = __builtin_amdgcn_mfma_f32_16x16x32_bf16(qa[0], b0, a, 0,0,0);
      a = __builtin_amdgcn_mfma_f32_16x16x32_bf16(qa[1], b1, a, 0,0,0);
      int k = kt*16 + c16;
      #pragma unroll
      for (int r=0; r<4; r++) p[kt][r] = (k < klen) ? a[r]*scl : -1e30f;
    }
    float m[4], sum[4];
    #pragma unroll
    for (int r=0; r<4; r++){
      float mm = p[0][r];
      #pragma unroll
      for (int kt=1; kt<8; kt++) mm = fmaxf(mm, p[kt][r]);
      for (int o=1; o<16; o<<=1) mm = fmaxf(mm, __shfl_xor(mm, o));
      m[r] = mm;
    }
    #pragma unroll
    for (int r=0; r<4; r++){
      float s = 0.f;
      #pragma unroll
      for (int kt=0; kt<8; kt++){ p[kt][r] = __expf(p[kt][r]-m[r]); s += p[kt][r]; }
      for (int o=1; o<16; o<<=1) s += __shfl_xor(s, o);
      sum[r] = 1.0f/s;
    }
    #pragma unroll
    for (int kt=0; kt<8; kt++)
      #pragma unroll
      for (int r=0; r<4; r++)
        Pws[w][(g16*4+r)*136 + kt*16 + c16] = f2bf(p[kt][r]*sum[r]);
    #pragma unroll
    for (int dt=0; dt<4; dt++){
      f32x4 o4 = {0.f,0.f,0.f,0.f};
      #pragma unroll
      for (int ks=0; ks<4; ks++){
        short8 pa = *(short8*)&Pws[w][c16*136 + ks*32 + g16*8];
        short8 vb = *(short8*)&Vt[(dt*16+c16)*136 + ks*32 + g16*8];
        o4 = __builtin_amdgcn_mfma_f32_16x16x32_bf16(pa, vb, o4, 0,0,0);
      }
      #pragma unroll
      for (int r=0; r<4; r++){
        int q2 = qbase + g16*4 + r;
        if (q2 < qlen){
          int col = hd0 + dt*16 + c16;
          float qv;
          if (QBF) qv = bf2f(((const ushort*)Qpv)[(size_t)g*qgstride + (size_t)q2*qstride + col]);
          else     qv = ((const float*)Qpv)[(size_t)g*qgstride + (size_t)q2*qstride + col];
          float ov = qv + o4[r];
          if (OBF) ((ushort*)Ov)[((size_t)g*qlen + q2)*HID + col] = f2bf(ov);
          else     ((float*)Ov)[((size_t)g*qlen + q2)*HID + col] = ov;
        }
      }
    }
  }
}

// ---------------------------------------------------------------------------
extern "C" void kernel_launch(void* const* d_in, const int* in_sizes, int n_in,
                              void* d_out, int out_size, void* d_ws, size_t ws_size,
                              hipStream_t stream)
{
  (void)in_sizes; (void)n_in; (void)out_size; (void)ws_size;
  const float* x      = (const float*)d_in[0];
  const int*   ei     = (const int*)d_in[1];
  const float* g0_W1=(const float*)d_in[3],  *g0_b1=(const float*)d_in[4],  *g0_ga1=(const float*)d_in[5],  *g0_be1=(const float*)d_in[6];
  const float* g0_W2=(const float*)d_in[7],  *g0_b2=(const float*)d_in[8],  *g0_ga2=(const float*)d_in[9],  *g0_be2=(const float*)d_in[10];
  const float* g1_W1=(const float*)d_in[11], *g1_b1=(const float*)d_in[12], *g1_ga1=(const float*)d_in[13], *g1_be1=(const float*)d_in[14];
  const float* g1_W2=(const float*)d_in[15], *g1_b2=(const float*)d_in[16], *g1_ga2=(const float*)d_in[17], *g1_be2=(const float*)d_in[18];
  const float* lin1_W=(const float*)d_in[19], *lin1_b=(const float*)d_in[20];
  const float* S1=(const float*)d_in[21];
  const float* p1_Wq=(const float*)d_in[22], *p1_Wk=(const float*)d_in[23], *p1_Wv=(const float*)d_in[24], *p1_Wo=(const float*)d_in[25];
  const float* p1_bq=(const float*)d_in[26], *p1_bk=(const float*)d_in[27], *p1_bv=(const float*)d_in[28], *p1_bo=(const float*)d_in[29];
  const float* s2_Wq=(const float*)d_in[30], *s2_Wk=(const float*)d_in[31], *s2_Wv=(const float*)d_in[32], *s2_Wo=(const float*)d_in[33];
  const float* s2_bq=(const float*)d_in[34], *s2_bk=(const float*)d_in[35], *s2_bv=(const float*)d_in[36], *s2_bo=(const float*)d_in[37];
  const float* p3_Wq=(const float*)d_in[38], *p3_Wk=(const float*)d_in[39], *p3_Wv=(const float*)d_in[40], *p3_Wo=(const float*)d_in[41];
  const float* p3_bq=(const float*)d_in[42], *p3_bk=(const float*)d_in[43], *p3_bv=(const float*)d_in[44], *p3_bo=(const float*)d_in[45];
  const float* S3=(const float*)d_in[46];
  const float* lin2_W=(const float*)d_in[47], *lin2_b=(const float*)d_in[48];

  const int* src = ei;
  const int* dst = ei + EDGES;

  // workspace layout (~147 MB)
  float* F = (float*)d_ws;
  const size_t SZ = (size_t)NTOT*HID;              // 8388608 floats
  float* R0=F, *R1=F+SZ, *R2=F+2*SZ, *R3=F+3*SZ;
  float* part  = F + 4*SZ;           // 262144 (512 row-blocks x 256, s2 +131072)
  float* stats = part + 262144;      // 512
  float* dinv  = stats + 512;        // 32768
  float* qp1   = dinv + 32768;       // 19200
  float* qp3   = qp1 + 19200;        // 256
  float* bcomb = qp3 + 256;          // 512 (combined lin1+KV bias)
  float* o3    = bcomb + 512;        // 65536 (bf16 O3 fits in first half)
  float* xf    = o3 + 65536;         // 65536
  float* tmpKV = xf + 65536;         // 131072 (2x 256x256 fp32 scratch)
  ushort* adjg = (ushort*)(tmpKV + 131072);        // GG*16384 bf16 = 8.39 MB
  ushort* wtb  = adjg + (size_t)GG*NN*NN;          // 16*65536 bf16

  const dim3 B256(256);
  const dim3 mmBig(512,2), mmMid(300,2);
  #define WT(i) (wtb + (size_t)(i)*65536)

  // --- FAT PREP: weights, adjacency, lin1-fold matmuls, comb bias, qp1, qp3 ---
  PrepArgs pa;
  pa.e[0]  = {g0_W1, 128, 256};
  pa.e[1]  = {g0_W2, 256, 256};
  pa.e[2]  = {g1_W1, 256, 256};
  pa.e[3]  = {g1_W2, 256, 256};
  pa.e[4]  = {lin1_W,256, 256};
  pa.e[5]  = {p1_Wk, 256, 256};
  pa.e[6]  = {p1_Wv, 256, 256};
  pa.e[7]  = {p1_Wo, 256, 256};
  pa.e[8]  = {s2_Wk, 256, 256};
  pa.e[9]  = {s2_Wv, 256, 256};
  pa.e[10] = {s2_Wq, 256, 256};
  pa.e[11] = {s2_Wo, 256, 256};
  pa.e[12] = {p3_Wk, 256, 256};
  pa.e[13] = {p3_Wv, 256, 256};
  pa.e[14] = {p3_Wo, 256, 256};
  pa.e[15] = {lin2_W,256, 128};
  float* tmpK = tmpKV;
  float* tmpV = tmpKV + 65536;
  fat_prep<<<dim3(558),B256,0,stream>>>(pa, wtb, src, dst, adjg, dinv,
      lin1_W, p1_Wk, p1_Wv, lin1_b, bcomb, tmpK, tmpV,
      S1, p1_Wq, p1_bq, qp1, S3, p3_Wq, p3_bq, qp3);
  {
    PrepArgs pc;
    pc.e[0] = {tmpK, 256, 256};
    pc.e[1] = {tmpV, 256, 256};
    prep_weights<<<dim3(2,16),B256,0,stream>>>(pc, WT(5));
  }

  // --- GIN layer 0 (reassociated: h1 = Adj@(x@W1) + b1) ---
  mm_bf16<0,0,0,1,0,0,0><<<mmBig,B256,0,stream>>>(x, WT(0), nullptr,nullptr,nullptr, nullptr, nullptr, nullptr, (ushort*)R1, nullptr, nullptr, NTOT,128,HID); // x@W1 planes -> R1
  agg_gemm<3,1><<<dim3(GG,2),B256,0,stream>>>(adjg, (ushort*)R1, nullptr, nullptr, g0_b1, nullptr, R0, nullptr, part); // h1 bf16 -> R0 (+bn partials)
  bn_final2<<<dim3(256),B256,0,stream>>>(part, g0_ga1, g0_be1, stats);
  // h1'' = relu(bn1(h1)) hoisted; then W2 GEMM (ATR=0) -> planes + bn partials
  bnrelu_bf<<<dim3(4096),B256,0,stream>>>((ushort*)R0, stats, (ushort*)R3);
  mm_bf16<0,0,1,1,1,0,0><<<mmBig,B256,0,stream>>>(R3, WT(1), g0_b2, nullptr,nullptr, nullptr, nullptr, nullptr, (ushort*)R2, nullptr, part, NTOT,256,HID);
  bn_final2<<<dim3(256),B256,0,stream>>>(part, g0_ga2, g0_be2, stats);

  // --- GIN layer 1 (bn2+outer-relu of layer0 fused at plane load) ---
  agg_gemm<1,1><<<dim3(GG,2),B256,0,stream>>>(adjg, (ushort*)R2, nullptr, stats, nullptr, nullptr, R0, nullptr, nullptr); // h1' bf16 -> R0
  mm_bf16<0,0,1,0,1,1,0><<<mmBig,B256,0,stream>>>(R0, WT(2), g1_b1, nullptr,nullptr, nullptr, nullptr, R1, nullptr, nullptr, part, NTOT,256,HID); // bf16 -> R1
  bn_final2<<<dim3(256),B256,0,stream>>>(part, g1_ga1, g1_be1, stats);
  // hoist bn1'+relu, then W2' (ATR=0)
  bnrelu_bf<<<dim3(4096),B256,0,stream>>>((ushort*)R1, stats, (ushort*)R3);
  mm_bf16<0,0,1,0,1,1,0><<<mmBig,B256,0,stream>>>(R3, WT(3), g1_b2, nullptr,nullptr, nullptr, nullptr, R2, nullptr, nullptr, part, NTOT,256,HID); // h2' bf16 -> R2
  bn_final2<<<dim3(256),B256,0,stream>>>(part, g1_ga2, g1_be2, stats);

  // --- h2'' = relu(bn2'(h2')) materialized once ---
  bnrelu_bf<<<dim3(4096),B256,0,stream>>>((ushort*)R2, stats, (ushort*)R1);

  // --- GMPool_G (p1): K,V planes from h2'' via folded lin1+KV weights ---
  mm_bf16<0,0,0,1,1,0,0><<<dim3(512,4),B256,0,stream>>>(R1, WT(5), bcomb, bcomb+256, nullptr, nullptr, nullptr, nullptr, (ushort*)R0, dinv, nullptr, NTOT,256,512);
  {
    void* Kb = (void*)R3;
    void* Vb = (void*)((ushort*)R3 + (size_t)NTOT*HID);
    agg_gemm<2,1><<<dim3(GG,4),B256,0,stream>>>(adjg, (ushort*)R0, (ushort*)R0 + (size_t)256*NTOT, dinv, p1_bk, p1_bv, Kb, Vb, nullptr); // bf16 Kd,Vd -> R3
    attn_mfma<1,0,1><<<dim3(GG,4),B256,0,stream>>>(qp1, Kb, Vb, (void*)R2, 75,128, 0, HID, HID);  // O1 bf16 -> R2
  }
  mm_bf16<1,0,0,0,1,1,1><<<mmMid,B256,0,stream>>>(R2, WT(7), p1_bo, nullptr,nullptr, R2, nullptr, R1, nullptr, nullptr, nullptr, 19200,256,HID); // Xp bf16 -> R1

  // --- SelfAtt (s2): ONE fused K|V|Q GEMM (N=768, all bf16 out) ---
  {
    ushort* KVQ = (ushort*)R0;                       // [19200][768] bf16 (29.5 MB)
    mm_bf16<0,0,0,0,1,1,0><<<dim3(300,6),B256,0,stream>>>(R1, WT(8), s2_bk, s2_bv, s2_bq, nullptr, nullptr, KVQ, nullptr, nullptr, nullptr, 19200,256,768);
    attn_mfma<1,1,1><<<dim3(GG,4),B256,0,stream>>>((const void*)(KVQ+512), (const void*)KVQ, (const void*)(KVQ+256), (void*)R3, 75,75, 75*768, 768, 768); // O2 bf16 -> R3
  }
  mm_bf16<1,0,0,0,1,1,1><<<mmMid,B256,0,stream>>>(R3, WT(11), s2_bo, nullptr,nullptr, R3, nullptr, R1, nullptr, nullptr, nullptr, 19200,256,HID); // Xp2 bf16 -> R1

  // --- GMPool_I (p3): fused K|V GEMM (bf16 A, N=512, bf16 out) ---
  {
    ushort* KV3 = (ushort*)R2;                       // [19200][512] bf16
    mm_bf16<0,0,0,0,1,1,0><<<dim3(300,4),B256,0,stream>>>(R1, WT(12), p3_bk, p3_bv, nullptr, nullptr, nullptr, KV3, nullptr, nullptr, nullptr, 19200,256,512);
    attn_mfma<1,0,1><<<dim3(GG,4),B256,0,stream>>>(qp3, (const void*)KV3, (const void*)(KV3+256), (void*)o3, 1,75, 0, HID, 512); // O3 bf16 -> o3
  }
  mm_bf16<1,0,0,0,1,1,1><<<dim3(4,2),B256,0,stream>>>(o3, WT(14), p3_bo, nullptr,nullptr, o3, nullptr, xf, nullptr, nullptr, nullptr, 256,256,HID); // xf bf16

  // --- lin2 ---
  mm_bf16<0,0,0,0,1,0,0><<<dim3(4,1),B256,0,stream>>>(xf, WT(15), lin2_b, nullptr,nullptr, nullptr, nullptr, (float*)d_out, nullptr, nullptr, nullptr, 256,256,128);
}